// Round 9
// baseline (206.324 us; speedup 1.0000x reference)
//
#include <hip/hip_runtime.h>

// MultiHeadSelfAttention: B=2, S=2048, E=1024, H=16, D=64
// bf16 MFMA pipeline. R9: attn pairs ADJACENT q-tiles {2i, 2i+1} (97% wave
// utilization, 30% fewer stagings vs {pi,31-pi}); LPT = big i first.
// GEMM2 gets BK=64 (16 MFMA per barrier-pair). Rest as R8.

typedef unsigned short u16;
typedef short bf16x8 __attribute__((ext_vector_type(8)));
typedef float f32x4 __attribute__((ext_vector_type(4)));
typedef unsigned short u16x4 __attribute__((ext_vector_type(4)));

#define S_LEN 2048
#define EMB 1024
#define NH 16
#define HD 64
#define QKV_W 3072
#define BATCH 2
#define CSC 0.18033688f  // 0.125 * log2(e)
#define PSTR 72          // plds row stride (64-wide P rows)

static __device__ __forceinline__ u16 f2bf(float f) {
    unsigned x = __float_as_uint(f);
    return (u16)((x + 0x7fffu + ((x >> 16) & 1u)) >> 16);
}

static __device__ __forceinline__ void gld_lds16(const u16* g, u16* l) {
    __builtin_amdgcn_global_load_lds(
        (const __attribute__((address_space(1))) void*)g,
        (__attribute__((address_space(3))) void*)l, 16, 0, 0);
}

// ---------------- fused fp32 -> bf16 casts (3 ranges) ----------------
#define XN4 (BATCH * S_LEN * EMB / 4)      // 1048576
#define WQ4 (QKV_W * EMB / 4)              // 786432
#define W04 (EMB * EMB / 4)                // 262144
__global__ __launch_bounds__(256) void cvt_all(const float* __restrict__ x,
                                               const float* __restrict__ wq,
                                               const float* __restrict__ w0,
                                               u16* __restrict__ xb,
                                               u16* __restrict__ wqb,
                                               u16* __restrict__ w0b) {
    int i = blockIdx.x * 256 + threadIdx.x;
    const float* src;
    u16* dst;
    int off;
    if (i < XN4) { src = x; dst = xb; off = i; }
    else if (i < XN4 + WQ4) { src = wq; dst = wqb; off = i - XN4; }
    else { src = w0; dst = w0b; off = i - XN4 - WQ4; }
    float4 v = ((const float4*)src)[off];
    u16x4 o;
    o[0] = f2bf(v.x); o[1] = f2bf(v.y); o[2] = f2bf(v.z); o[3] = f2bf(v.w);
    ((u16x4*)dst)[off] = o;
}

// ---------------- GEMM: C[M,N] = A[M,K] @ Bt[N,K]^T ----------------
// BM=128, BN/BK templated, 256 thr / 4 waves.
// Columns n < qcols scaled by CSC (Q pre-scaling for attention).
template <typename OutT, int BN, int BK>
__global__ __launch_bounds__(256) void gemm_bt(const u16* __restrict__ A,
                                               const u16* __restrict__ Bt,
                                               OutT* __restrict__ C,
                                               int M, int N, int K, int qcols) {
    constexpr int NF = BN / 32;        // n-frags per wave
    constexpr int KH = BK / 32;        // k-halves per LDS tile
    constexpr int ACH = 128 * BK / 2048;  // A staging chunks per thread
    constexpr int BCH = BN * BK / 2048;   // B staging chunks per thread
    __shared__ alignas(16) u16 As[128 * BK];
    __shared__ alignas(16) u16 Bs[BN * BK];
    const int tid = threadIdx.x;
    const int wave = tid >> 6, lane = tid & 63;
    const int quad = lane >> 4, lr = lane & 15;
    const int m0 = blockIdx.y * 128, n0 = blockIdx.x * BN;
    const int wm = (wave & 1) * 64, wn = (wave >> 1) * (BN / 2);
    const float sc = (n0 < qcols) ? CSC : 1.0f;

    f32x4 acc[4][NF] = {};

    for (int k0 = 0; k0 < K; k0 += BK) {
#pragma unroll
        for (int i = 0; i < ACH; ++i) {
            int chunk = tid + i * 256;
            int row = chunk / (BK / 8);
            int col8 = (chunk % (BK / 8)) * 8;
            gld_lds16(&A[(size_t)(m0 + row) * K + k0 + col8], &As[row * BK + col8]);
        }
#pragma unroll
        for (int i = 0; i < BCH; ++i) {
            int chunk = tid + i * 256;
            int row = chunk / (BK / 8);
            int col8 = (chunk % (BK / 8)) * 8;
            gld_lds16(&Bt[(size_t)(n0 + row) * K + k0 + col8], &Bs[row * BK + col8]);
        }
        __syncthreads();
#pragma unroll
        for (int kh = 0; kh < KH; ++kh) {
            bf16x8 af[4], bf[NF];
#pragma unroll
            for (int i = 0; i < 4; ++i)
                af[i] = *(const bf16x8*)&As[(wm + i * 16 + lr) * BK + kh * 32 + quad * 8];
#pragma unroll
            for (int i = 0; i < NF; ++i)
                bf[i] = *(const bf16x8*)&Bs[(wn + i * 16 + lr) * BK + kh * 32 + quad * 8];
#pragma unroll
            for (int mi = 0; mi < 4; ++mi)
#pragma unroll
                for (int ni = 0; ni < NF; ++ni)
                    acc[mi][ni] = __builtin_amdgcn_mfma_f32_16x16x32_bf16(
                        af[mi], bf[ni], acc[mi][ni], 0, 0, 0);
        }
        __syncthreads();
    }

#pragma unroll
    for (int mi = 0; mi < 4; ++mi) {
#pragma unroll
        for (int r = 0; r < 4; ++r) {
            int gr = m0 + wm + mi * 16 + quad * 4 + r;
#pragma unroll
            for (int ni = 0; ni < NF; ++ni) {
                int gc = n0 + wn + ni * 16 + lr;
                float v = acc[mi][ni][r] * sc;
                if constexpr (sizeof(OutT) == 2)
                    C[(size_t)gr * N + gc] = (OutT)f2bf(v);
                else
                    C[(size_t)gr * N + gc] = (OutT)v;
            }
        }
    }
}

// ---------------- V transpose: qkv[.,2048+h*64+d] -> vt[bh][d][s] ----------------
__global__ __launch_bounds__(256) void transpose_v(const u16* __restrict__ qkv,
                                                   u16* __restrict__ vt) {
    __shared__ alignas(16) u16 t[64][72];
    const int s0 = blockIdx.x * 64;
    const int bh = blockIdx.y;
    const int b = bh >> 4, h = bh & 15;
#pragma unroll
    for (int i = 0; i < 2; ++i) {
        int chunk = threadIdx.x + i * 256;
        int row = chunk >> 3;
        int c8 = (chunk & 7) * 8;
        uint4 v = *(const uint4*)&qkv[(size_t)(b * S_LEN + s0 + row) * QKV_W +
                                      2 * EMB + h * HD + c8];
        const u16* p = (const u16*)&v;
#pragma unroll
        for (int jj = 0; jj < 8; ++jj) t[c8 + jj][row] = p[jj];
    }
    __syncthreads();
#pragma unroll
    for (int i = 0; i < 2; ++i) {
        int chunk = threadIdx.x + i * 256;
        int d = chunk >> 3;
        int c8 = (chunk & 7) * 8;
        uint4 v = *(const uint4*)&t[d][c8];
        *(uint4*)&vt[((size_t)bh * HD + d) * S_LEN + s0 + c8] = v;
    }
}

// ---------------- Flash attention (causal), R9 ----------------
// grid (16, 32), 512 thr = 8 waves. Block index i (LPT: i = 15-bx, heavy
// first) owns ADJACENT q-tiles qtA=2i (waves 0-3), qtB=2i+1 (waves 4-7);
// shared KV staging j=0..qtB -> 97% wave utilization. Double-buffered
// Ks/Vs, one barrier/iter. Waves 0-3 stage K, 4-7 stage V. p = exp2(s).
__global__ __launch_bounds__(512, 4) void attn(const u16* __restrict__ qkv,
                                               const u16* __restrict__ vt,
                                               u16* __restrict__ e) {
    const int tid = threadIdx.x;
    const int w = tid >> 6, lane = tid & 63;
    const int quad = lane >> 4, lr = lane & 15;
    const int i = 15 - (int)blockIdx.x;  // LPT: heavy blocks dispatch first
    const int qtA = 2 * i, qtB = 2 * i + 1;
    const int bh = blockIdx.y, b = bh >> 4, h = bh & 15;
    const int myqt = (w < 4) ? qtA : qtB;
    const int qbase = myqt * 64 + (w & 3) * 16;

    __shared__ alignas(16) u16 Ks[2 * 2 * 64 * 32];  // [buf][d-half][kv row][32]
    __shared__ alignas(16) u16 Vs[2 * 2 * 64 * 32];  // [buf][kv-half][d row][32]
    __shared__ alignas(16) u16 plds[8][16 * PSTR];
    u16* pw = plds[w];

    const u16* qkv_b = qkv + (size_t)b * S_LEN * QKV_W;
    const u16* qrow = qkv_b + (size_t)(qbase + lr) * QKV_W + h * HD + quad * 8;
    const bf16x8 qf0 = *(const bf16x8*)(qrow);
    const bf16x8 qf1 = *(const bf16x8*)(qrow + 32);

    const u16* kbase = qkv_b + EMB + h * HD;          // K[s][d], stride 3072
    const u16* vbase = vt + (size_t)bh * HD * S_LEN;  // V^T[d][s], stride 2048

    f32x4 o[4] = {};
    float lsum = 0.f;
    const int qg = qbase + lr;

    // staging role: waves 0-3 -> K rows, waves 4-7 -> V rows
    const int sr = (w & 3) * 16 + (lane >> 2);  // row 0..63
    const int sc = (lane & 3) * 8;              // 0,8,16,24

    auto stage = [&](int j, int bb) {
        const int kv0 = j * 64;
        if (w < 4) {
            gld_lds16(kbase + (size_t)(kv0 + sr) * QKV_W + sc,
                      &Ks[bb * 4096 + sr * 32 + sc]);
            gld_lds16(kbase + (size_t)(kv0 + sr) * QKV_W + 32 + sc,
                      &Ks[bb * 4096 + 2048 + sr * 32 + sc]);
        } else {
            gld_lds16(vbase + (size_t)sr * S_LEN + kv0 + sc,
                      &Vs[bb * 4096 + sr * 32 + sc]);
            gld_lds16(vbase + (size_t)sr * S_LEN + kv0 + 32 + sc,
                      &Vs[bb * 4096 + 2048 + sr * 32 + sc]);
        }
    };

    stage(0, 0);
    for (int j = 0; j <= qtB; ++j) {
        const int bb = j & 1;
        __syncthreads();  // staged buf bb complete (vmcnt drained at barrier)
        if (j < qtB) stage(j + 1, 1 - bb);
        if (j <= myqt) {
            const int kv0 = j * 64;
            const u16* ks = &Ks[bb * 4096];
            const u16* vs = &Vs[bb * 4096];
            // ---- S^T: lane holds S[q=lr][kv=kv0+nt*16+quad*4+r] ----
            f32x4 s[4];
#pragma unroll
            for (int nt = 0; nt < 4; ++nt) {
                bf16x8 k0 = *(const bf16x8*)&ks[(nt * 16 + lr) * 32 + quad * 8];
                bf16x8 k1 = *(const bf16x8*)&ks[2048 + (nt * 16 + lr) * 32 + quad * 8];
                f32x4 z = {};
                z = __builtin_amdgcn_mfma_f32_16x16x32_bf16(k0, qf0, z, 0, 0, 0);
                z = __builtin_amdgcn_mfma_f32_16x16x32_bf16(k1, qf1, z, 0, 0, 0);
                s[nt] = z;
            }
            // ---- softmax: p = exp2(s); mask on the diagonal tile ----
            const bool diag = (j == myqt);
            __builtin_amdgcn_wave_barrier();
#pragma unroll
            for (int nt = 0; nt < 4; ++nt) {
                float p[4];
#pragma unroll
                for (int r = 0; r < 4; ++r) {
                    float pv = exp2f(s[nt][r]);
                    if (diag) pv = (kv0 + nt * 16 + quad * 4 + r > qg) ? 0.f : pv;
                    p[r] = pv;
                }
                lsum += (p[0] + p[1]) + (p[2] + p[3]);
                uint2 pk;  // truncation pack: hi16 of each float
                pk.x = __builtin_amdgcn_perm(__float_as_uint(p[1]),
                                             __float_as_uint(p[0]), 0x07060302u);
                pk.y = __builtin_amdgcn_perm(__float_as_uint(p[3]),
                                             __float_as_uint(p[2]), 0x07060302u);
                *(uint2*)&pw[lr * PSTR + nt * 16 + quad * 4] = pk;
            }
            __builtin_amdgcn_wave_barrier();
            const bf16x8 p0 = *(const bf16x8*)&pw[lr * PSTR + quad * 8];
            const bf16x8 p1 = *(const bf16x8*)&pw[lr * PSTR + 32 + quad * 8];
            // ---- O += P @ V ----
#pragma unroll
            for (int nt = 0; nt < 4; ++nt) {
                bf16x8 v0 = *(const bf16x8*)&vs[(nt * 16 + lr) * 32 + quad * 8];
                bf16x8 v1 = *(const bf16x8*)&vs[2048 + (nt * 16 + lr) * 32 + quad * 8];
                o[nt] = __builtin_amdgcn_mfma_f32_16x16x32_bf16(p0, v0, o[nt], 0, 0, 0);
                o[nt] = __builtin_amdgcn_mfma_f32_16x16x32_bf16(p1, v1, o[nt], 0, 0, 0);
            }
        }
    }

    // ---- finalize: l = quad-reduce(lsum); e = O / l ----
    float lf = lsum + __shfl_xor(lsum, 16, 64);
    lf += __shfl_xor(lf, 32, 64);
#pragma unroll
    for (int r = 0; r < 4; ++r) {
        float inv = 1.0f / __shfl(lf, quad * 4 + r, 64);
        size_t row = (size_t)(b * S_LEN + qbase + quad * 4 + r) * EMB + h * HD;
#pragma unroll
        for (int nt = 0; nt < 4; ++nt)
            e[row + nt * 16 + lr] = f2bf(o[nt][r] * inv);
    }
}

// ---------------- launcher ----------------
extern "C" void kernel_launch(void* const* d_in, const int* in_sizes, int n_in,
                              void* d_out, int out_size, void* d_ws, size_t ws_size,
                              hipStream_t stream) {
    const float* x = (const float*)d_in[0];
    const float* w_qkv = (const float*)d_in[1];
    const float* w0 = (const float*)d_in[2];
    float* out = (float*)d_out;

    const size_t M = (size_t)BATCH * S_LEN;  // 4096
    u16* xb = (u16*)d_ws;
    u16* wqb = xb + M * EMB;
    u16* w0b = wqb + (size_t)QKV_W * EMB;
    u16* qkvb = w0b + (size_t)EMB * EMB;
    u16* vtb = qkvb + M * QKV_W;
    u16* eb = vtb + (size_t)BATCH * NH * HD * S_LEN;

    cvt_all<<<(XN4 + WQ4 + W04) / 256, 256, 0, stream>>>(x, w_qkv, w0, xb, wqb, w0b);

    // qkv = x @ w_qkv^T; Q columns pre-scaled by CSC
    gemm_bt<u16, 128, 32><<<dim3(QKV_W / 128, M / 128), 256, 0, stream>>>(
        xb, wqb, qkvb, (int)M, QKV_W, EMB, EMB);

    transpose_v<<<dim3(S_LEN / 64, BATCH * NH), 256, 0, stream>>>(qkvb, vtb);

    attn<<<dim3(16, BATCH * NH), 512, 0, stream>>>(qkvb, vtb, eb);

    // out = e @ w0^T (128x64 tiles, BK=64 -> 512 blocks, 16 MFMA/barrier)
    gemm_bt<float, 64, 64><<<dim3(EMB / 64, M / 128), 256, 0, stream>>>(
        eb, w0b, out, (int)M, EMB, EMB, 0);
}

// Round 10
// 189.630 us; speedup vs baseline: 1.0880x; 1.0880x over previous
//
#include <hip/hip_runtime.h>

// MultiHeadSelfAttention: B=2, S=2048, E=1024, H=16, D=64
// bf16 MFMA pipeline. R10: attn = R8 pairing {pi, 31-pi} (compute-uniform:
// 132 wave-iters/block) + swizzled (bx,by)->(pi,bh) so co-resident blocks
// (c, c+256) get complementary pi -> per-CU staging uniform at 49 iters.

typedef unsigned short u16;
typedef short bf16x8 __attribute__((ext_vector_type(8)));
typedef float f32x4 __attribute__((ext_vector_type(4)));
typedef unsigned short u16x4 __attribute__((ext_vector_type(4)));

#define S_LEN 2048
#define EMB 1024
#define NH 16
#define HD 64
#define QKV_W 3072
#define BATCH 2
#define CSC 0.18033688f  // 0.125 * log2(e)
#define PSTR 72          // plds row stride (64-wide P rows)

static __device__ __forceinline__ u16 f2bf(float f) {
    unsigned x = __float_as_uint(f);
    return (u16)((x + 0x7fffu + ((x >> 16) & 1u)) >> 16);
}

static __device__ __forceinline__ void gld_lds16(const u16* g, u16* l) {
    __builtin_amdgcn_global_load_lds(
        (const __attribute__((address_space(1))) void*)g,
        (__attribute__((address_space(3))) void*)l, 16, 0, 0);
}

// ---------------- fused fp32 -> bf16 casts (3 ranges) ----------------
#define XN4 (BATCH * S_LEN * EMB / 4)      // 1048576
#define WQ4 (QKV_W * EMB / 4)              // 786432
#define W04 (EMB * EMB / 4)                // 262144
__global__ __launch_bounds__(256) void cvt_all(const float* __restrict__ x,
                                               const float* __restrict__ wq,
                                               const float* __restrict__ w0,
                                               u16* __restrict__ xb,
                                               u16* __restrict__ wqb,
                                               u16* __restrict__ w0b) {
    int i = blockIdx.x * 256 + threadIdx.x;
    const float* src;
    u16* dst;
    int off;
    if (i < XN4) { src = x; dst = xb; off = i; }
    else if (i < XN4 + WQ4) { src = wq; dst = wqb; off = i - XN4; }
    else { src = w0; dst = w0b; off = i - XN4 - WQ4; }
    float4 v = ((const float4*)src)[off];
    u16x4 o;
    o[0] = f2bf(v.x); o[1] = f2bf(v.y); o[2] = f2bf(v.z); o[3] = f2bf(v.w);
    ((u16x4*)dst)[off] = o;
}

// ---------------- GEMM: C[M,N] = A[M,K] @ Bt[N,K]^T ----------------
// BM=128, BN/BK templated, 256 thr / 4 waves.
// Columns n < qcols scaled by CSC (Q pre-scaling for attention).
template <typename OutT, int BN, int BK>
__global__ __launch_bounds__(256) void gemm_bt(const u16* __restrict__ A,
                                               const u16* __restrict__ Bt,
                                               OutT* __restrict__ C,
                                               int M, int N, int K, int qcols) {
    constexpr int NF = BN / 32;        // n-frags per wave
    constexpr int KH = BK / 32;        // k-halves per LDS tile
    constexpr int ACH = 128 * BK / 2048;  // A staging chunks per thread
    constexpr int BCH = BN * BK / 2048;   // B staging chunks per thread
    __shared__ alignas(16) u16 As[128 * BK];
    __shared__ alignas(16) u16 Bs[BN * BK];
    const int tid = threadIdx.x;
    const int wave = tid >> 6, lane = tid & 63;
    const int quad = lane >> 4, lr = lane & 15;
    const int m0 = blockIdx.y * 128, n0 = blockIdx.x * BN;
    const int wm = (wave & 1) * 64, wn = (wave >> 1) * (BN / 2);
    const float sc = (n0 < qcols) ? CSC : 1.0f;

    f32x4 acc[4][NF] = {};

    for (int k0 = 0; k0 < K; k0 += BK) {
#pragma unroll
        for (int i = 0; i < ACH; ++i) {
            int chunk = tid + i * 256;
            int row = chunk / (BK / 8);
            int col8 = (chunk % (BK / 8)) * 8;
            gld_lds16(&A[(size_t)(m0 + row) * K + k0 + col8], &As[row * BK + col8]);
        }
#pragma unroll
        for (int i = 0; i < BCH; ++i) {
            int chunk = tid + i * 256;
            int row = chunk / (BK / 8);
            int col8 = (chunk % (BK / 8)) * 8;
            gld_lds16(&Bt[(size_t)(n0 + row) * K + k0 + col8], &Bs[row * BK + col8]);
        }
        __syncthreads();
#pragma unroll
        for (int kh = 0; kh < KH; ++kh) {
            bf16x8 af[4], bf[NF];
#pragma unroll
            for (int i = 0; i < 4; ++i)
                af[i] = *(const bf16x8*)&As[(wm + i * 16 + lr) * BK + kh * 32 + quad * 8];
#pragma unroll
            for (int i = 0; i < NF; ++i)
                bf[i] = *(const bf16x8*)&Bs[(wn + i * 16 + lr) * BK + kh * 32 + quad * 8];
#pragma unroll
            for (int mi = 0; mi < 4; ++mi)
#pragma unroll
                for (int ni = 0; ni < NF; ++ni)
                    acc[mi][ni] = __builtin_amdgcn_mfma_f32_16x16x32_bf16(
                        af[mi], bf[ni], acc[mi][ni], 0, 0, 0);
        }
        __syncthreads();
    }

#pragma unroll
    for (int mi = 0; mi < 4; ++mi) {
#pragma unroll
        for (int r = 0; r < 4; ++r) {
            int gr = m0 + wm + mi * 16 + quad * 4 + r;
#pragma unroll
            for (int ni = 0; ni < NF; ++ni) {
                int gc = n0 + wn + ni * 16 + lr;
                float v = acc[mi][ni][r] * sc;
                if constexpr (sizeof(OutT) == 2)
                    C[(size_t)gr * N + gc] = (OutT)f2bf(v);
                else
                    C[(size_t)gr * N + gc] = (OutT)v;
            }
        }
    }
}

// ---------------- V transpose: qkv[.,2048+h*64+d] -> vt[bh][d][s] ----------------
__global__ __launch_bounds__(256) void transpose_v(const u16* __restrict__ qkv,
                                                   u16* __restrict__ vt) {
    __shared__ alignas(16) u16 t[64][72];
    const int s0 = blockIdx.x * 64;
    const int bh = blockIdx.y;
    const int b = bh >> 4, h = bh & 15;
#pragma unroll
    for (int i = 0; i < 2; ++i) {
        int chunk = threadIdx.x + i * 256;
        int row = chunk >> 3;
        int c8 = (chunk & 7) * 8;
        uint4 v = *(const uint4*)&qkv[(size_t)(b * S_LEN + s0 + row) * QKV_W +
                                      2 * EMB + h * HD + c8];
        const u16* p = (const u16*)&v;
#pragma unroll
        for (int jj = 0; jj < 8; ++jj) t[c8 + jj][row] = p[jj];
    }
    __syncthreads();
#pragma unroll
    for (int i = 0; i < 2; ++i) {
        int chunk = threadIdx.x + i * 256;
        int d = chunk >> 3;
        int c8 = (chunk & 7) * 8;
        uint4 v = *(const uint4*)&t[d][c8];
        *(uint4*)&vt[((size_t)bh * HD + d) * S_LEN + s0 + c8] = v;
    }
}

// ---------------- Flash attention (causal), R10 ----------------
// grid (16, 32), 512 thr = 8 waves. Pairing {pi, 31-pi}: waves 0-3 own
// tile A=pi, waves 4-7 own tile B=31-pi (132 wave-iters/block, uniform).
// Swizzle: flip=(by>>4)&1, pi=flip?15-bx:bx, bh=((by&15)<<1)|flip -> the
// two co-resident blocks (c, c+256) have complementary pi, so per-CU
// staging totals are uniform (49 iters). Double-buffered Ks/Vs, one
// barrier/iter; waves 0-3 stage K, 4-7 stage V; p = exp2(s), Q pre-scaled.
__global__ __launch_bounds__(512, 4) void attn(const u16* __restrict__ qkv,
                                               const u16* __restrict__ vt,
                                               u16* __restrict__ e) {
    const int tid = threadIdx.x;
    const int w = tid >> 6, lane = tid & 63;
    const int quad = lane >> 4, lr = lane & 15;
    const int bx = blockIdx.x, by = blockIdx.y;
    const int flip = (by >> 4) & 1;
    const int pi = flip ? (15 - bx) : bx;
    const int bh = ((by & 15) << 1) | flip;
    const int qtA = pi, qtB = 31 - pi;
    const int b = bh >> 4, h = bh & 15;
    const int myqt = (w < 4) ? qtA : qtB;
    const int qbase = myqt * 64 + (w & 3) * 16;

    __shared__ alignas(16) u16 Ks[2 * 2 * 64 * 32];  // [buf][d-half][kv row][32]
    __shared__ alignas(16) u16 Vs[2 * 2 * 64 * 32];  // [buf][kv-half][d row][32]
    __shared__ alignas(16) u16 plds[8][16 * PSTR];
    u16* pw = plds[w];

    const u16* qkv_b = qkv + (size_t)b * S_LEN * QKV_W;
    const u16* qrow = qkv_b + (size_t)(qbase + lr) * QKV_W + h * HD + quad * 8;
    const bf16x8 qf0 = *(const bf16x8*)(qrow);
    const bf16x8 qf1 = *(const bf16x8*)(qrow + 32);

    const u16* kbase = qkv_b + EMB + h * HD;          // K[s][d], stride 3072
    const u16* vbase = vt + (size_t)bh * HD * S_LEN;  // V^T[d][s], stride 2048

    f32x4 o[4] = {};
    float lsum = 0.f;
    const int qg = qbase + lr;

    // staging role: waves 0-3 -> K rows, waves 4-7 -> V rows
    const int sr = (w & 3) * 16 + (lane >> 2);  // row 0..63
    const int sc = (lane & 3) * 8;              // 0,8,16,24

    auto stage = [&](int j, int bb) {
        const int kv0 = j * 64;
        if (w < 4) {
            gld_lds16(kbase + (size_t)(kv0 + sr) * QKV_W + sc,
                      &Ks[bb * 4096 + sr * 32 + sc]);
            gld_lds16(kbase + (size_t)(kv0 + sr) * QKV_W + 32 + sc,
                      &Ks[bb * 4096 + 2048 + sr * 32 + sc]);
        } else {
            gld_lds16(vbase + (size_t)sr * S_LEN + kv0 + sc,
                      &Vs[bb * 4096 + sr * 32 + sc]);
            gld_lds16(vbase + (size_t)sr * S_LEN + kv0 + 32 + sc,
                      &Vs[bb * 4096 + 2048 + sr * 32 + sc]);
        }
    };

    stage(0, 0);
    for (int j = 0; j <= qtB; ++j) {
        const int bb = j & 1;
        __syncthreads();  // staged buf bb complete (vmcnt drained at barrier)
        if (j < qtB) stage(j + 1, 1 - bb);
        if (j <= myqt) {
            const int kv0 = j * 64;
            const u16* ks = &Ks[bb * 4096];
            const u16* vs = &Vs[bb * 4096];
            // ---- S^T: lane holds S[q=lr][kv=kv0+nt*16+quad*4+r] ----
            f32x4 s[4];
#pragma unroll
            for (int nt = 0; nt < 4; ++nt) {
                bf16x8 k0 = *(const bf16x8*)&ks[(nt * 16 + lr) * 32 + quad * 8];
                bf16x8 k1 = *(const bf16x8*)&ks[2048 + (nt * 16 + lr) * 32 + quad * 8];
                f32x4 z = {};
                z = __builtin_amdgcn_mfma_f32_16x16x32_bf16(k0, qf0, z, 0, 0, 0);
                z = __builtin_amdgcn_mfma_f32_16x16x32_bf16(k1, qf1, z, 0, 0, 0);
                s[nt] = z;
            }
            // ---- softmax: p = exp2(s); mask on the diagonal tile ----
            const bool diag = (j == myqt);
            __builtin_amdgcn_wave_barrier();
#pragma unroll
            for (int nt = 0; nt < 4; ++nt) {
                float p[4];
#pragma unroll
                for (int r = 0; r < 4; ++r) {
                    float pv = exp2f(s[nt][r]);
                    if (diag) pv = (kv0 + nt * 16 + quad * 4 + r > qg) ? 0.f : pv;
                    p[r] = pv;
                }
                lsum += (p[0] + p[1]) + (p[2] + p[3]);
                uint2 pk;  // truncation pack: hi16 of each float
                pk.x = __builtin_amdgcn_perm(__float_as_uint(p[1]),
                                             __float_as_uint(p[0]), 0x07060302u);
                pk.y = __builtin_amdgcn_perm(__float_as_uint(p[3]),
                                             __float_as_uint(p[2]), 0x07060302u);
                *(uint2*)&pw[lr * PSTR + nt * 16 + quad * 4] = pk;
            }
            __builtin_amdgcn_wave_barrier();
            const bf16x8 p0 = *(const bf16x8*)&pw[lr * PSTR + quad * 8];
            const bf16x8 p1 = *(const bf16x8*)&pw[lr * PSTR + 32 + quad * 8];
            // ---- O += P @ V ----
#pragma unroll
            for (int nt = 0; nt < 4; ++nt) {
                bf16x8 v0 = *(const bf16x8*)&vs[(nt * 16 + lr) * 32 + quad * 8];
                bf16x8 v1 = *(const bf16x8*)&vs[2048 + (nt * 16 + lr) * 32 + quad * 8];
                o[nt] = __builtin_amdgcn_mfma_f32_16x16x32_bf16(p0, v0, o[nt], 0, 0, 0);
                o[nt] = __builtin_amdgcn_mfma_f32_16x16x32_bf16(p1, v1, o[nt], 0, 0, 0);
            }
        }
    }

    // ---- finalize: l = quad-reduce(lsum); e = O / l ----
    float lf = lsum + __shfl_xor(lsum, 16, 64);
    lf += __shfl_xor(lf, 32, 64);
#pragma unroll
    for (int r = 0; r < 4; ++r) {
        float inv = 1.0f / __shfl(lf, quad * 4 + r, 64);
        size_t row = (size_t)(b * S_LEN + qbase + quad * 4 + r) * EMB + h * HD;
#pragma unroll
        for (int nt = 0; nt < 4; ++nt)
            e[row + nt * 16 + lr] = f2bf(o[nt][r] * inv);
    }
}

// ---------------- launcher ----------------
extern "C" void kernel_launch(void* const* d_in, const int* in_sizes, int n_in,
                              void* d_out, int out_size, void* d_ws, size_t ws_size,
                              hipStream_t stream) {
    const float* x = (const float*)d_in[0];
    const float* w_qkv = (const float*)d_in[1];
    const float* w0 = (const float*)d_in[2];
    float* out = (float*)d_out;

    const size_t M = (size_t)BATCH * S_LEN;  // 4096
    u16* xb = (u16*)d_ws;
    u16* wqb = xb + M * EMB;
    u16* w0b = wqb + (size_t)QKV_W * EMB;
    u16* qkvb = w0b + (size_t)EMB * EMB;
    u16* vtb = qkvb + M * QKV_W;
    u16* eb = vtb + (size_t)BATCH * NH * HD * S_LEN;

    cvt_all<<<(XN4 + WQ4 + W04) / 256, 256, 0, stream>>>(x, w_qkv, w0, xb, wqb, w0b);

    // qkv = x @ w_qkv^T; Q columns pre-scaled by CSC
    gemm_bt<u16, 128, 32><<<dim3(QKV_W / 128, M / 128), 256, 0, stream>>>(
        xb, wqb, qkvb, (int)M, QKV_W, EMB, EMB);

    transpose_v<<<dim3(S_LEN / 64, BATCH * NH), 256, 0, stream>>>(qkvb, vtb);

    attn<<<dim3(16, BATCH * NH), 512, 0, stream>>>(qkvb, vtb, eb);

    // out = e @ w0^T (128x64 tiles, BK=64 -> 512 blocks, 16 MFMA/barrier)
    gemm_bt<float, 64, 64><<<dim3(EMB / 64, M / 128), 256, 0, stream>>>(
        eb, w0b, out, (int)M, EMB, EMB, 0);
}